// Round 24
// baseline (127.655 us; speedup 1.0000x reference)
//
#include <hip/hip_runtime.h>

#define Nn 4096
#define FIN 512
#define NH 8
#define O1 512
#define LOG2E 1.44269504088896f

typedef __attribute__((ext_vector_type(8))) _Float16 half8;
typedef __attribute__((ext_vector_type(2))) _Float16 h2;
typedef __attribute__((ext_vector_type(4))) float f32x4;
typedef __attribute__((ext_vector_type(2))) unsigned int u32x2;
typedef unsigned long long ull;

__device__ __forceinline__ unsigned short f2bf(float f){
  union{float f; unsigned u;} x; x.f=f;
  unsigned r = x.u + 0x7fffu + ((x.u>>16)&1u);
  return (unsigned short)(r>>16);
}
__device__ __forceinline__ float bf2f(unsigned short b){
  union{unsigned u; float f;} x; x.u=((unsigned)b)<<16;
  return x.f;
}
__device__ __forceinline__ h2 pkrtz(float a, float b){
  return __builtin_bit_cast(h2, __builtin_amdgcn_cvt_pkrtz(a, b));
}
__device__ __forceinline__ h2 pkmul(h2 a, h2 b){
  h2 r; asm("v_pk_mul_f16 %0,%1,%2":"=v"(r):"v"(a),"v"(b)); return r;
}
__device__ __forceinline__ h2 pkmax(h2 a, h2 b){
  h2 r; asm("v_pk_max_f16 %0,%1,%2":"=v"(r):"v"(a),"v"(b)); return r;
}
// {sext(bit 2k), sext(bit 2k+1)} packed as 2x16-bit mask
__device__ __forceinline__ unsigned pairmask(unsigned bits, int k){
  unsigned s = ((bits >> (2*k)) * 0x8001u) & 0x10001u;
  return s * 0xFFFFu;
}
__device__ __forceinline__ void gload_lds16(const unsigned short* g, unsigned short* l){
  __builtin_amdgcn_global_load_lds(
      (const __attribute__((address_space(1))) unsigned int*)g,
      (__attribute__((address_space(3))) unsigned int*)l, 16, 0, 0);
}

// ---- pack adjacency int32 -> bitmask (grid-stride, 2048 blocks) ----
__global__ void k_pack_adj(const int* __restrict__ adj, ull* __restrict__ adjw){
  const size_t total = (size_t)Nn*Nn;
  const size_t stride = (size_t)gridDim.x*blockDim.x;
  for (size_t tid = (size_t)blockIdx.x*blockDim.x + threadIdx.x; tid < total; tid += stride){
    int v = __builtin_nontemporal_load(adj + tid);
    ull m = __ballot(v>0);
    if((threadIdx.x&63)==0) adjw[tid>>6] = m;
  }
}

// ---- fused f32 -> f16 convert for x, W, W2 ----
__global__ void k_cvt_all(const float* __restrict__ x, const float* __restrict__ W,
                          const float* __restrict__ W2,
                          unsigned short* __restrict__ xb, unsigned short* __restrict__ Wb,
                          unsigned short* __restrict__ W2b){
  const int NX = Nn*FIN, NW = O1*FIN, NW2 = 64*FIN;
  int i = (blockIdx.x*blockDim.x + threadIdx.x)*4;
  const float* src; unsigned short* dst; int off;
  if (i < NX){ src=x; dst=xb; off=i; }
  else if (i < NX+NW){ src=W; dst=Wb; off=i-NX; }
  else if (i < NX+NW+NW2){ src=W2; dst=W2b; off=i-NX-NW; }
  else return;
  float4 v = *(const float4*)(src+off);
  h2 lo = pkrtz(v.x, v.y);
  h2 hi = pkrtz(v.z, v.w);
  u32x2 pk; pk.x = __builtin_bit_cast(unsigned, lo); pk.y = __builtin_bit_cast(unsigned, hi);
  *(u32x2*)(dst+off) = pk;
}

// ---- K-split GEMM (f16): C^T[o][m] = sum_k A[m][k]*B[o][k] ----
template<int NWC, int KS>
__global__ __launch_bounds__(NWC*KS*64, 4)
void k_gemm3(const unsigned short* __restrict__ A, const unsigned short* __restrict__ B,
             unsigned short* __restrict__ CT, int M, int K, int O){
  int t=threadIdx.x, l=t&63, w=t>>6;
  int wc=w%NWC, ks=w/NWC;
  int m0=blockIdx.x*32, o0=blockIdx.y*(NWC*32);
  int row=l&15, kq=(l>>4)*8, g=l>>4;
  int kw=K/KS;
  const unsigned short* Ab = A + (size_t)(m0+row)*K + ks*kw + kq;
  const unsigned short* Bb = B + (size_t)(o0+wc*32+row)*K + ks*kw + kq;
  f32x4 acc[2][2]={};
  #pragma unroll 2
  for(int k0=0;k0<kw;k0+=32){
    half8 a0=*(const half8*)(Ab+k0);
    half8 a1=*(const half8*)(Ab+(size_t)16*K+k0);
    half8 b0=*(const half8*)(Bb+k0);
    half8 b1=*(const half8*)(Bb+(size_t)16*K+k0);
    acc[0][0]=__builtin_amdgcn_mfma_f32_16x16x32_f16(a0,b0,acc[0][0],0,0,0);
    acc[0][1]=__builtin_amdgcn_mfma_f32_16x16x32_f16(a0,b1,acc[0][1],0,0,0);
    acc[1][0]=__builtin_amdgcn_mfma_f32_16x16x32_f16(a1,b0,acc[1][0],0,0,0);
    acc[1][1]=__builtin_amdgcn_mfma_f32_16x16x32_f16(a1,b1,acc[1][1],0,0,0);
  }
  __shared__ float red[NWC][KS/2][32][36];
  for(int s=KS/2;s>=1;s>>=1){
    if(ks>=s && ks<2*s){
      #pragma unroll
      for(int mi=0;mi<2;mi++)
      #pragma unroll
      for(int oi=0;oi<2;oi++)
      #pragma unroll
      for(int r=0;r<4;r++)
        red[wc][ks-s][mi*16+g*4+r][oi*18+row]=acc[mi][oi][r];
    }
    __syncthreads();
    if(ks<s){
      #pragma unroll
      for(int mi=0;mi<2;mi++)
      #pragma unroll
      for(int oi=0;oi<2;oi++)
      #pragma unroll
      for(int r=0;r<4;r++)
        acc[mi][oi][r]+=red[wc][ks][mi*16+g*4+r][oi*18+row];
    }
    __syncthreads();
  }
  if(ks==0){
    #pragma unroll
    for(int mi=0;mi<2;mi++)
    #pragma unroll
    for(int oi=0;oi<2;oi++){
      int m=m0+mi*16+g*4;
      int o=o0+wc*32+oi*16+row;
      h2 lo = pkrtz(acc[mi][oi][0], acc[mi][oi][1]);
      h2 hi = pkrtz(acc[mi][oi][2], acc[mi][oi][3]);
      u32x2 pk; pk.x=__builtin_bit_cast(unsigned, lo); pk.y=__builtin_bit_cast(unsigned, hi);
      *(u32x2*)&CT[(size_t)o*M+m] = pk;
    }
  }
}

// ---- per-node score factors: row AoS f32 {E1,F1}; col f16 planes E2[],F2[] ----
__global__ void k_wh12(const unsigned short* __restrict__ whT,
                       const float* __restrict__ a1, const float* __restrict__ a2,
                       float2* __restrict__ e1f1, unsigned short* __restrict__ E2a,
                       unsigned short* __restrict__ F2a){
  const int M=Nn;
  int n=blockIdx.x*blockDim.x+threadIdx.x;
  int h=blockIdx.y;
  float s1=0.f,s2=0.f;
  for(int c=0;c<64;c++){
    float v=(float)__builtin_bit_cast(_Float16, whT[(size_t)(h*64+c)*M+n]);
    s1+=v*a1[h*64+c];
    s2+=v*a2[h*64+c];
  }
  float s1L=s1*LOG2E, s2L=s2*LOG2E;
  float2 r1; r1.x=__builtin_amdgcn_exp2f(s1L); r1.y=__builtin_amdgcn_exp2f(0.2f*s1L);
  e1f1[(size_t)h*M+n]=r1;
  E2a[(size_t)h*M+n]=__builtin_bit_cast(unsigned short,(_Float16)__builtin_amdgcn_exp2f(s2L));
  F2a[(size_t)h*M+n]=__builtin_bit_cast(unsigned short,(_Float16)__builtin_amdgcn_exp2f(0.2f*s2L));
}

// ---- fused attention v15: RF=4 (1 wave per 64 q-rows), 2 waves/block (jw
// split), ring-2 V, f16 packed P, EF in LDS, per-step vmcnt(0) drain.
// Halves per-CU LDS-read traffic: each wave's 8 bfr reads/step feed 4 rf.
template<int JSTEPS, int LOGH, int JCLOG, int FINAL>
__global__ __launch_bounds__(128, 2)
void k_attn15(const ull* __restrict__ adjw,
              const float2* __restrict__ e1f1,
              const unsigned short* __restrict__ E2a,
              const unsigned short* __restrict__ F2a,
              const unsigned short* __restrict__ whT,
              unsigned short* __restrict__ Hmat,
              unsigned short* __restrict__ Opart, float* __restrict__ Dpart){
  const int M = Nn;
  __shared__ __align__(16) unsigned short vbuf[2][2][64][64];     // 32KB V ring-2
  __shared__ __align__(16) unsigned short efbuf[2][2][JSTEPS*64]; // E/F f16 planes
  int t = threadIdx.x, l = t & 63, jw = t >> 6;   // 2 waves: jw in {0,1}
  int lr = l & 15, g = l >> 4;
  int bid = blockIdx.x;
  int h = bid & ((1<<LOGH)-1);
  int bx = bid >> LOGH;
  int jc = bx & ((1<<JCLOG)-1);
  int rowtile = bx >> JCLOG;
  int i_base = rowtile*64;                        // this block's 64 rows (all waves)
  int jbase = jc*(2*JSTEPS*64) + jw*(JSTEPS*64);
  const unsigned short* Vb = whT + (size_t)h*64*M;

  h2 E1h[4], F1h[4];
  const ull* ar[4];
  #pragma unroll
  for (int rf=0; rf<4; rf++){
    int i = i_base + rf*16 + lr;
    float2 a = e1f1[(size_t)h*M + i];
    E1h[rf] = pkrtz(a.x, a.x);
    F1h[rf] = pkrtz(a.y, a.y);
    ar[rf] = adjw + (size_t)i*64 + (jbase>>6);
  }

  // V staging: this wave stages ALL 64 c-rows of its jw tile (8 gloads).
  // pre-swizzled source: phys group l&7 holds logical group (l&7)^(row&7)
  const unsigned short* vs[8];
  #pragma unroll
  for (int k=0;k<8;k++){
    int rloc = k*8 + (l>>3);
    vs[k] = Vb + (size_t)rloc*M + jbase + (((l&7)^(rloc&7))<<3);
  }

  // EF staging: this wave stages BOTH planes of its j-range
  {
    constexpr int PB = JSTEPS*128;           // plane bytes
    constexpr int NB = (PB + 1023)/1024;
    #pragma unroll
    for (int p=0;p<2;p++){
      const unsigned short* src = (p ? F2a : E2a) + (size_t)h*M + jbase;
      unsigned short* dst = &efbuf[jw][p][0];
      #pragma unroll
      for (int b=0;b<NB;b++){
        if (b*1024 + l*16 < PB)
          gload_lds16(src + b*512 + l*8, dst + b*512);
      }
    }
  }

  half8 ones;
  #pragma unroll
  for (int q=0;q<8;q++) ones[q] = (_Float16)1.0f;

  f32x4 acc[4][4] = {};
  f32x4 accd[4] = {};

  #define STAGEV(slot, off) do{ \
      gload_lds16(vs[0] + (off)*64, &vbuf[jw][slot][ 0][0]); \
      gload_lds16(vs[1] + (off)*64, &vbuf[jw][slot][ 8][0]); \
      gload_lds16(vs[2] + (off)*64, &vbuf[jw][slot][16][0]); \
      gload_lds16(vs[3] + (off)*64, &vbuf[jw][slot][24][0]); \
      gload_lds16(vs[4] + (off)*64, &vbuf[jw][slot][32][0]); \
      gload_lds16(vs[5] + (off)*64, &vbuf[jw][slot][40][0]); \
      gload_lds16(vs[6] + (off)*64, &vbuf[jw][slot][48][0]); \
      gload_lds16(vs[7] + (off)*64, &vbuf[jw][slot][56][0]); \
    }while(0)

  // prologue: stage tile 0 + EF planes; drain; barrier
  STAGEV(0,0);
  ull w0[4];
  #pragma unroll
  for (int rf=0; rf<4; rf++) w0[rf] = ar[rf][0];
  asm volatile("s_waitcnt vmcnt(0)" ::: "memory");
  __builtin_amdgcn_sched_barrier(0);
  __builtin_amdgcn_s_barrier();

  const unsigned short* efE = &efbuf[jw][0][g*8];
  const unsigned short* efF = &efbuf[jw][1][g*8];

  for (int s0 = 0; s0 < JSTEPS; s0 += 4){
    #pragma unroll
    for (int u = 0; u < 4; u++){
      int s = s0 + u;
      // adj prefetch + next-tile stage (lands during this step's compute)
      ull wn[4] = {};
      if (s+1 < JSTEPS){
        #pragma unroll
        for (int rf=0; rf<4; rf++) wn[rf] = ar[rf][u+1];
        STAGEV((u+1)&1, u+1);
      }
      // ---- packed-f16 P compute from LDS E/F planes (4 rf) ----
      union { f32x4 f; h2 hh[4]; } Ee[2], Ff[2];
      #pragma unroll
      for (int half=0; half<2; half++){
        Ee[half].f = *(const f32x4*)(efE + u*64 + half*32);
        Ff[half].f = *(const f32x4*)(efF + u*64 + half*32);
      }
      unsigned pu[4][2][4];
      #pragma unroll
      for (int half=0; half<2; half++){
        unsigned bits[4];
        #pragma unroll
        for (int rf=0; rf<4; rf++) bits[rf] = (unsigned)(w0[rf] >> (half*32 + g*8)) & 0xffu;
        #pragma unroll
        for (int k=0;k<4;k++){
          h2 e2 = Ee[half].hh[k], f2v = Ff[half].hh[k];
          #pragma unroll
          for (int rf=0; rf<4; rf++){
            h2 p = pkmax(pkmul(E1h[rf], e2), pkmul(F1h[rf], f2v));
            pu[rf][half][k] = __builtin_bit_cast(unsigned, p) & pairmask(bits[rf],k);
          }
        }
      }
      // ---- MFMA phase: ring slot u&1 (static), swizzled conflict-free reads,
      // 8 bfr reads serve ALL 4 rf ----
      __builtin_amdgcn_s_setprio(1);
      #pragma unroll
      for (int half=0; half<2; half++){
        half8 bfr[4];
        #pragma unroll
        for (int ct=0; ct<4; ct++)
          bfr[ct] = *(const half8*)&vbuf[jw][u&1][ct*16+lr][(((half*4+g)^(lr&7))<<3)];
        #pragma unroll
        for (int rf=0; rf<4; rf++){
          union { unsigned uu[4]; half8 v; } pv_;
          #pragma unroll
          for (int k=0;k<4;k++) pv_.uu[k] = pu[rf][half][k];
          #pragma unroll
          for (int ct=0; ct<4; ct++)
            acc[rf][ct] = __builtin_amdgcn_mfma_f32_16x16x32_f16(pv_.v, bfr[ct], acc[rf][ct], 0,0,0);
          accd[rf] = __builtin_amdgcn_mfma_f32_16x16x32_f16(pv_.v, ones, accd[rf], 0,0,0);
        }
      }
      __builtin_amdgcn_s_setprio(0);
      if (s+1 < JSTEPS){
        #pragma unroll
        for (int rf=0; rf<4; rf++) w0[rf] = wn[rf];
      }
      // drain this step's stage (mostly landed under compute), then barrier
      asm volatile("s_waitcnt vmcnt(0)" ::: "memory");
      __builtin_amdgcn_sched_barrier(0);
      __builtin_amdgcn_s_barrier();
    }
    #pragma unroll
    for (int k=0;k<8;k++) vs[k] += 256;
    #pragma unroll
    for (int rf=0; rf<4; rf++) ar[rf] += 4;
    efE += 256; efF += 256;
  }
  #undef STAGEV

  // ---- in-block j-combine (jw1 -> jw0; alias onto vbuf, stride 65) ----
  float* cmb  = (float*)&vbuf[0][0][0][0];       // 64 x 65 f32 = 16.6KB (<32KB)
  float* cmbD = cmb + 64*65;
  __syncthreads();                               // loop done
  if (jw == 1){
    #pragma unroll
    for (int rf=0; rf<4; rf++){
      #pragma unroll
      for (int ct=0; ct<4; ct++)
        #pragma unroll
        for (int r=0; r<4; r++)
          cmb[(rf*16 + g*4 + r)*65 + ct*16 + lr] = acc[rf][ct][r];
      if (lr == 0){
        #pragma unroll
        for (int r=0; r<4; r++)
          cmbD[rf*16 + g*4 + r] = accd[rf][r];
      }
    }
  }
  __syncthreads();
  if (jw == 0){
    #pragma unroll
    for (int rf=0; rf<4; rf++){
      #pragma unroll
      for (int r=0; r<4; r++){
        int rloc = rf*16 + g*4 + r;
        float d = accd[rf][r] + cmbD[rloc];
        float rd = 1.f / fmaxf(d, 1e-30f);
        int row = rowtile*64 + rloc;
        if (FINAL){
          size_t pbase = (size_t)((h<<JCLOG)|jc)*Nn + row;
          if (lr == 0) Dpart[pbase] = d;
          #pragma unroll
          for (int ct=0; ct<4; ct++){
            float v = acc[rf][ct][r] + cmb[rloc*65 + ct*16 + lr];
            Opart[pbase*64 + ct*16 + lr] = f2bf(v);   // raw partial (bf16: range)
          }
        } else {
          #pragma unroll
          for (int ct=0; ct<4; ct++){
            float v = (acc[rf][ct][r] + cmb[rloc*65 + ct*16 + lr]) * rd;
            v = v > 0.f ? v : __expf(v) - 1.f;   // ELU
            Hmat[(size_t)row*O1 + h*64 + ct*16 + lr] =
                __builtin_bit_cast(unsigned short, (_Float16)v);
          }
        }
      }
    }
  }
}

// ---- layer-1 finish: combine 2 j-chunks, normalize, ELU -> Hmat (f16) ----
__global__ void k_fin1(const unsigned short* __restrict__ Op, const float* __restrict__ Dp,
                       unsigned short* __restrict__ Hmat){
  int t = threadIdx.x;
  int c = t & 63, rr = t >> 6;
  int row = blockIdx.x*4 + rr, h = blockIdx.y;
  size_t b0 = (size_t)(h*2+0)*Nn + row;
  size_t b1 = (size_t)(h*2+1)*Nn + row;
  float o = bf2f(Op[b0*64+c]) + bf2f(Op[b1*64+c]);
  float d = Dp[b0] + Dp[b1];
  float v = o / fmaxf(d, 1e-30f);
  v = v > 0.f ? v : __expf(v) - 1.f;
  Hmat[(size_t)row*O1 + h*64 + c] = __builtin_bit_cast(unsigned short, (_Float16)v);
}

// ---- layer-2 finish: combine 8 j-chunks, normalize, ELU, log_softmax ----
__global__ void k_fin2(const unsigned short* __restrict__ Op, const float* __restrict__ Dp,
                       float* __restrict__ out){
  int w = threadIdx.x>>6, l = threadIdx.x&63;
  int row = blockIdx.x*4 + w;
  float o = 0.f, d = 0.f;
  #pragma unroll
  for (int jc=0; jc<8; jc++){
    o += bf2f(Op[((size_t)jc*Nn + row)*64 + l]);
    d += Dp[(size_t)jc*Nn + row];
  }
  float v = o / fmaxf(d, 1e-30f);
  v = v > 0.f ? v : __expf(v) - 1.f;
  float m = v;
  #pragma unroll
  for (int dd=1; dd<64; dd<<=1) m = fmaxf(m, __shfl_xor(m, dd));
  float s = __expf(v - m);
  #pragma unroll
  for (int dd=1; dd<64; dd<<=1) s += __shfl_xor(s, dd);
  out[(size_t)row*64 + l] = v - (m + __logf(s));
}

extern "C" void kernel_launch(void* const* d_in, const int* in_sizes, int n_in,
                              void* d_out, int out_size, void* d_ws, size_t ws_size,
                              hipStream_t stream){
  const float* x  = (const float*)d_in[0];
  const int* adj  = (const int*)d_in[1];
  const float* W  = (const float*)d_in[2];
  const float* a1 = (const float*)d_in[3];
  const float* a2 = (const float*)d_in[4];
  const float* W2 = (const float*)d_in[5];
  const float* a21= (const float*)d_in[6];
  const float* a22= (const float*)d_in[7];
  float* out = (float*)d_out;
  char* ws = (char*)d_ws;

  size_t off=0;
  ull* adjw = (ull*)(ws+off); off += (size_t)Nn*64*8;                                 // 2MB
  unsigned short* xb   = (unsigned short*)(ws+off); off += (size_t)Nn*FIN*2;          // 4MB
  unsigned short* Wb   = (unsigned short*)(ws+off); off += (size_t)O1*FIN*2;          // .5MB
  unsigned short* W2b  = (unsigned short*)(ws+off); off += (size_t)64*FIN*2;          // 64KB
  unsigned short* whT1 = (unsigned short*)(ws+off); off += (size_t)O1*Nn*2;           // 4MB
  unsigned short* Hmat = (unsigned short*)(ws+off); off += (size_t)Nn*O1*2;           // 4MB
  unsigned short* whT2 = (unsigned short*)(ws+off); off += (size_t)64*Nn*2;           // .5MB
  float2* e1f1a = (float2*)(ws+off); off += (size_t)NH*Nn*8;
  unsigned short* E2aa = (unsigned short*)(ws+off); off += (size_t)NH*Nn*2;
  unsigned short* F2aa = (unsigned short*)(ws+off); off += (size_t)NH*Nn*2;
  float2* e1f1b = (float2*)(ws+off); off += (size_t)Nn*8;
  unsigned short* E2ab = (unsigned short*)(ws+off); off += (size_t)Nn*2;
  unsigned short* F2ab = (unsigned short*)(ws+off); off += (size_t)Nn*2;
  // partials: 16 slots x Nn x 64 bf16 (8MB) + 16 x Nn fp32 (256KB)
  unsigned short* Opart = (unsigned short*)(ws+off); off += (size_t)16*Nn*64*2;
  float* Dpart = (float*)(ws+off); off += (size_t)16*Nn*4;

  k_pack_adj<<<2048, 256, 0, stream>>>(adj, adjw);
  {
    int tot = (Nn*FIN + O1*FIN + 64*FIN)/4;
    k_cvt_all<<<(tot+255)/256, 256, 0, stream>>>(x, W, W2, xb, Wb, W2b);
  }
  k_gemm3<2,4><<<dim3(Nn/32, O1/64), 512, 0, stream>>>(xb, Wb, whT1, Nn, FIN, O1);
  k_wh12<<<dim3(Nn/256, NH), 256, 0, stream>>>(whT1, a1, a2, e1f1a, E2aa, F2aa);
  // layer-1 attention: 64 rowtiles x 2 j-chunks x 8 heads = 1024 blocks x 128thr
  k_attn15<16, 3, 1, 1><<<(Nn/64)*2*NH, 128, 0, stream>>>(adjw, e1f1a, E2aa, F2aa, whT1, nullptr, Opart, Dpart);
  k_fin1<<<dim3(Nn/4, NH), 256, 0, stream>>>(Opart, Dpart, Hmat);
  // layer-2 projection: o-tile 32, grid 128x2 = 256 blocks
  k_gemm3<1,8><<<dim3(Nn/32, 2), 512, 0, stream>>>(Hmat, W2b, whT2, Nn, FIN, 64);
  k_wh12<<<dim3(Nn/256, 1), 256, 0, stream>>>(whT2, a21, a22, e1f1b, E2ab, F2ab);
  // layer-2 attention: 64 rowtiles x 8 j-chunks = 512 blocks x 128thr -> partials
  k_attn15<4, 0, 3, 1><<<(Nn/64)*8, 128, 0, stream>>>(adjw, e1f1b, E2ab, F2ab, whT2, nullptr, Opart, Dpart);
  k_fin2<<<Nn/4, 256, 0, stream>>>(Opart, Dpart, out);
  (void)in_sizes; (void)n_in; (void)out_size; (void)ws_size;
}

// Round 25
// 113.499 us; speedup vs baseline: 1.1247x; 1.1247x over previous
//
#include <hip/hip_runtime.h>

#define Nn 4096
#define FIN 512
#define NH 8
#define O1 512
#define LOG2E 1.44269504088896f

typedef __attribute__((ext_vector_type(8))) _Float16 half8;
typedef __attribute__((ext_vector_type(2))) _Float16 h2;
typedef __attribute__((ext_vector_type(4))) float f32x4;
typedef __attribute__((ext_vector_type(2))) unsigned int u32x2;
typedef unsigned long long ull;

__device__ __forceinline__ unsigned short f2bf(float f){
  union{float f; unsigned u;} x; x.f=f;
  unsigned r = x.u + 0x7fffu + ((x.u>>16)&1u);
  return (unsigned short)(r>>16);
}
__device__ __forceinline__ float bf2f(unsigned short b){
  union{unsigned u; float f;} x; x.u=((unsigned)b)<<16;
  return x.f;
}
__device__ __forceinline__ h2 pkrtz(float a, float b){
  return __builtin_bit_cast(h2, __builtin_amdgcn_cvt_pkrtz(a, b));
}
__device__ __forceinline__ h2 pkmul(h2 a, h2 b){
  h2 r; asm("v_pk_mul_f16 %0,%1,%2":"=v"(r):"v"(a),"v"(b)); return r;
}
__device__ __forceinline__ h2 pkmax(h2 a, h2 b){
  h2 r; asm("v_pk_max_f16 %0,%1,%2":"=v"(r):"v"(a),"v"(b)); return r;
}
// {sext(bit 2k), sext(bit 2k+1)} packed as 2x16-bit mask
__device__ __forceinline__ unsigned pairmask(unsigned bits, int k){
  unsigned s = ((bits >> (2*k)) * 0x8001u) & 0x10001u;
  return s * 0xFFFFu;
}
__device__ __forceinline__ void gload_lds16(const unsigned short* g, unsigned short* l){
  __builtin_amdgcn_global_load_lds(
      (const __attribute__((address_space(1))) unsigned int*)g,
      (__attribute__((address_space(3))) unsigned int*)l, 16, 0, 0);
}

// ---- pack adjacency int32 -> bitmask (grid-stride, 2048 blocks) ----
__global__ void k_pack_adj(const int* __restrict__ adj, ull* __restrict__ adjw){
  const size_t total = (size_t)Nn*Nn;
  const size_t stride = (size_t)gridDim.x*blockDim.x;
  for (size_t tid = (size_t)blockIdx.x*blockDim.x + threadIdx.x; tid < total; tid += stride){
    int v = __builtin_nontemporal_load(adj + tid);
    ull m = __ballot(v>0);
    if((threadIdx.x&63)==0) adjw[tid>>6] = m;
  }
}

// ---- fused f32 -> f16 convert for x, W, W2 ----
__global__ void k_cvt_all(const float* __restrict__ x, const float* __restrict__ W,
                          const float* __restrict__ W2,
                          unsigned short* __restrict__ xb, unsigned short* __restrict__ Wb,
                          unsigned short* __restrict__ W2b){
  const int NX = Nn*FIN, NW = O1*FIN, NW2 = 64*FIN;
  int i = (blockIdx.x*blockDim.x + threadIdx.x)*4;
  const float* src; unsigned short* dst; int off;
  if (i < NX){ src=x; dst=xb; off=i; }
  else if (i < NX+NW){ src=W; dst=Wb; off=i-NX; }
  else if (i < NX+NW+NW2){ src=W2; dst=W2b; off=i-NX-NW; }
  else return;
  float4 v = *(const float4*)(src+off);
  h2 lo = pkrtz(v.x, v.y);
  h2 hi = pkrtz(v.z, v.w);
  u32x2 pk; pk.x = __builtin_bit_cast(unsigned, lo); pk.y = __builtin_bit_cast(unsigned, hi);
  *(u32x2*)(dst+off) = pk;
}

// ---- K-split GEMM (f16): C^T[o][m] = sum_k A[m][k]*B[o][k] ----
template<int NWC, int KS>
__global__ __launch_bounds__(NWC*KS*64, 4)
void k_gemm3(const unsigned short* __restrict__ A, const unsigned short* __restrict__ B,
             unsigned short* __restrict__ CT, int M, int K, int O){
  int t=threadIdx.x, l=t&63, w=t>>6;
  int wc=w%NWC, ks=w/NWC;
  int m0=blockIdx.x*32, o0=blockIdx.y*(NWC*32);
  int row=l&15, kq=(l>>4)*8, g=l>>4;
  int kw=K/KS;
  const unsigned short* Ab = A + (size_t)(m0+row)*K + ks*kw + kq;
  const unsigned short* Bb = B + (size_t)(o0+wc*32+row)*K + ks*kw + kq;
  f32x4 acc[2][2]={};
  #pragma unroll 2
  for(int k0=0;k0<kw;k0+=32){
    half8 a0=*(const half8*)(Ab+k0);
    half8 a1=*(const half8*)(Ab+(size_t)16*K+k0);
    half8 b0=*(const half8*)(Bb+k0);
    half8 b1=*(const half8*)(Bb+(size_t)16*K+k0);
    acc[0][0]=__builtin_amdgcn_mfma_f32_16x16x32_f16(a0,b0,acc[0][0],0,0,0);
    acc[0][1]=__builtin_amdgcn_mfma_f32_16x16x32_f16(a0,b1,acc[0][1],0,0,0);
    acc[1][0]=__builtin_amdgcn_mfma_f32_16x16x32_f16(a1,b0,acc[1][0],0,0,0);
    acc[1][1]=__builtin_amdgcn_mfma_f32_16x16x32_f16(a1,b1,acc[1][1],0,0,0);
  }
  __shared__ float red[NWC][KS/2][32][36];
  for(int s=KS/2;s>=1;s>>=1){
    if(ks>=s && ks<2*s){
      #pragma unroll
      for(int mi=0;mi<2;mi++)
      #pragma unroll
      for(int oi=0;oi<2;oi++)
      #pragma unroll
      for(int r=0;r<4;r++)
        red[wc][ks-s][mi*16+g*4+r][oi*18+row]=acc[mi][oi][r];
    }
    __syncthreads();
    if(ks<s){
      #pragma unroll
      for(int mi=0;mi<2;mi++)
      #pragma unroll
      for(int oi=0;oi<2;oi++)
      #pragma unroll
      for(int r=0;r<4;r++)
        acc[mi][oi][r]+=red[wc][ks][mi*16+g*4+r][oi*18+row];
    }
    __syncthreads();
  }
  if(ks==0){
    #pragma unroll
    for(int mi=0;mi<2;mi++)
    #pragma unroll
    for(int oi=0;oi<2;oi++){
      int m=m0+mi*16+g*4;
      int o=o0+wc*32+oi*16+row;
      h2 lo = pkrtz(acc[mi][oi][0], acc[mi][oi][1]);
      h2 hi = pkrtz(acc[mi][oi][2], acc[mi][oi][3]);
      u32x2 pk; pk.x=__builtin_bit_cast(unsigned, lo); pk.y=__builtin_bit_cast(unsigned, hi);
      *(u32x2*)&CT[(size_t)o*M+m] = pk;
    }
  }
}

// ---- per-node score factors: row AoS f32 {E1,F1}; col f16 planes E2[],F2[] ----
__global__ void k_wh12(const unsigned short* __restrict__ whT,
                       const float* __restrict__ a1, const float* __restrict__ a2,
                       float2* __restrict__ e1f1, unsigned short* __restrict__ E2a,
                       unsigned short* __restrict__ F2a){
  const int M=Nn;
  int n=blockIdx.x*blockDim.x+threadIdx.x;
  int h=blockIdx.y;
  float s1=0.f,s2=0.f;
  for(int c=0;c<64;c++){
    float v=(float)__builtin_bit_cast(_Float16, whT[(size_t)(h*64+c)*M+n]);
    s1+=v*a1[h*64+c];
    s2+=v*a2[h*64+c];
  }
  float s1L=s1*LOG2E, s2L=s2*LOG2E;
  float2 r1; r1.x=__builtin_amdgcn_exp2f(s1L); r1.y=__builtin_amdgcn_exp2f(0.2f*s1L);
  e1f1[(size_t)h*M+n]=r1;
  E2a[(size_t)h*M+n]=__builtin_bit_cast(unsigned short,(_Float16)__builtin_amdgcn_exp2f(s2L));
  F2a[(size_t)h*M+n]=__builtin_bit_cast(unsigned short,(_Float16)__builtin_amdgcn_exp2f(0.2f*s2L));
}

// ---- fused attention v14 (R22-proven): ring-2 V (32KB; total LDS 48KB ->
// 3 blocks/CU), f16 packed P, EF in LDS, per-step vmcnt(0) drain.
// Step s: reads slot s&1, stages tile s+1 into slot (s+1)&1, drain, barrier.
template<int JSTEPS, int LOGH, int JCLOG, int FINAL>
__global__ __launch_bounds__(256, 3)
void k_attn14(const ull* __restrict__ adjw,
              const float2* __restrict__ e1f1,
              const unsigned short* __restrict__ E2a,
              const unsigned short* __restrict__ F2a,
              const unsigned short* __restrict__ whT,
              unsigned short* __restrict__ Hmat,
              unsigned short* __restrict__ Opart, float* __restrict__ Dpart){
  const int M = Nn;
  __shared__ __align__(16) unsigned short vbuf[2][2][64][64];   // 32KB V ring-2
  __shared__ __align__(16) unsigned short efbuf[2][2][JSTEPS*64]; // E/F f16 planes
  int t = threadIdx.x, l = t & 63, w = t >> 6;
  int rw = w & 1, jw = w >> 1;
  int lr = l & 15, g = l >> 4;
  int bid = blockIdx.x;
  int h = bid & ((1<<LOGH)-1);
  int bx = bid >> LOGH;
  int jc = bx & ((1<<JCLOG)-1);
  int rowtile = bx >> JCLOG;
  int i_base = rowtile*64 + rw*32;
  int jbase = jc*(2*JSTEPS*64) + jw*(JSTEPS*64);
  const unsigned short* Vb = whT + (size_t)h*64*M;

  h2 E1h[2], F1h[2];
  const ull *ar0, *ar1;
  {
    int i0 = i_base + lr, i1 = i_base + 16 + lr;
    float2 a = e1f1[(size_t)h*M + i0];
    float2 b = e1f1[(size_t)h*M + i1];
    E1h[0] = pkrtz(a.x, a.x);
    F1h[0] = pkrtz(a.y, a.y);
    E1h[1] = pkrtz(b.x, b.x);
    F1h[1] = pkrtz(b.y, b.y);
    ar0 = adjw + (size_t)i0*64 + (jbase>>6);
    ar1 = adjw + (size_t)i1*64 + (jbase>>6);
  }

  // V staging sources (pre-swizzled: phys group l&7 holds logical (l&7)^(row&7))
  const unsigned short* vs[4];
  #pragma unroll
  for (int k=0;k<4;k++){
    int rloc = rw*32 + k*8 + (l>>3);
    vs[k] = Vb + (size_t)rloc*M + jbase + (((l&7)^(rloc&7))<<3);
  }

  // E/F plane staging: rw0 -> E plane, rw1 -> F plane of this jw's j-range
  {
    const unsigned short* src = (rw ? F2a : E2a) + (size_t)h*M + jbase;
    unsigned short* dst = &efbuf[jw][rw][0];
    constexpr int PB = JSTEPS*128;           // plane bytes
    constexpr int NB = (PB + 1023)/1024;
    #pragma unroll
    for (int b=0;b<NB;b++){
      if (b*1024 + l*16 < PB)
        gload_lds16(src + b*512 + l*8, dst + b*512);
    }
  }

  half8 ones;
  #pragma unroll
  for (int q=0;q<8;q++) ones[q] = (_Float16)1.0f;

  f32x4 acc[2][4] = {};
  f32x4 accd[2] = {};

  #define STAGEV(slot, off) do{ \
      gload_lds16(vs[0] + (off)*64, &vbuf[jw][slot][rw*32   ][0]); \
      gload_lds16(vs[1] + (off)*64, &vbuf[jw][slot][rw*32+ 8][0]); \
      gload_lds16(vs[2] + (off)*64, &vbuf[jw][slot][rw*32+16][0]); \
      gload_lds16(vs[3] + (off)*64, &vbuf[jw][slot][rw*32+24][0]); \
    }while(0)

  // prologue: stage tile 0 + EF planes; drain; barrier
  STAGEV(0,0);
  ull w0 = ar0[0], w1 = ar1[0];
  asm volatile("s_waitcnt vmcnt(0)" ::: "memory");
  __builtin_amdgcn_sched_barrier(0);
  __builtin_amdgcn_s_barrier();

  const unsigned short* efE = &efbuf[jw][0][g*8];
  const unsigned short* efF = &efbuf[jw][1][g*8];

  for (int s0 = 0; s0 < JSTEPS; s0 += 4){
    #pragma unroll
    for (int u = 0; u < 4; u++){
      int s = s0 + u;
      // adj prefetch + next-tile stage (lands during this step's compute)
      ull wn0=0, wn1=0;
      if (s+1 < JSTEPS){
        wn0 = ar0[u+1]; wn1 = ar1[u+1];
        STAGEV((u+1)&1, u+1);
      }
      // ---- packed-f16 P compute from LDS E/F planes ----
      union { f32x4 f; h2 hh[4]; } Ee[2], Ff[2];
      #pragma unroll
      for (int half=0; half<2; half++){
        Ee[half].f = *(const f32x4*)(efE + u*64 + half*32);
        Ff[half].f = *(const f32x4*)(efF + u*64 + half*32);
      }
      unsigned pu[2][2][4];
      #pragma unroll
      for (int half=0; half<2; half++){
        unsigned bits0 = (unsigned)(w0 >> (half*32 + g*8)) & 0xffu;
        unsigned bits1 = (unsigned)(w1 >> (half*32 + g*8)) & 0xffu;
        #pragma unroll
        for (int k=0;k<4;k++){
          h2 e2 = Ee[half].hh[k], f2v = Ff[half].hh[k];
          h2 p0 = pkmax(pkmul(E1h[0], e2), pkmul(F1h[0], f2v));
          h2 p1 = pkmax(pkmul(E1h[1], e2), pkmul(F1h[1], f2v));
          pu[0][half][k] = __builtin_bit_cast(unsigned, p0) & pairmask(bits0,k);
          pu[1][half][k] = __builtin_bit_cast(unsigned, p1) & pairmask(bits1,k);
        }
      }
      // ---- MFMA phase: ring slot u&1 (static), swizzled conflict-free reads ----
      __builtin_amdgcn_s_setprio(1);
      #pragma unroll
      for (int half=0; half<2; half++){
        half8 bfr[4];
        #pragma unroll
        for (int ct=0; ct<4; ct++)
          bfr[ct] = *(const half8*)&vbuf[jw][u&1][ct*16+lr][(((half*4+g)^(lr&7))<<3)];
        #pragma unroll
        for (int rf=0; rf<2; rf++){
          union { unsigned uu[4]; half8 v; } pv_;
          #pragma unroll
          for (int k=0;k<4;k++) pv_.uu[k] = pu[rf][half][k];
          #pragma unroll
          for (int ct=0; ct<4; ct++)
            acc[rf][ct] = __builtin_amdgcn_mfma_f32_16x16x32_f16(pv_.v, bfr[ct], acc[rf][ct], 0,0,0);
          accd[rf] = __builtin_amdgcn_mfma_f32_16x16x32_f16(pv_.v, ones, accd[rf], 0,0,0);
        }
      }
      __builtin_amdgcn_s_setprio(0);
      if (s+1 < JSTEPS){ w0 = wn0; w1 = wn1; }
      // drain this step's stage (mostly landed under compute), then barrier
      asm volatile("s_waitcnt vmcnt(0)" ::: "memory");
      __builtin_amdgcn_sched_barrier(0);
      __builtin_amdgcn_s_barrier();
    }
    #pragma unroll
    for (int k=0;k<4;k++) vs[k] += 256;
    ar0 += 4; ar1 += 4;
    efE += 256; efF += 256;
  }
  #undef STAGEV

  // ---- in-block j-combine (alias onto vbuf; stride 65 -> <=2-way banks) ----
  float* cmb  = (float*)&vbuf[0][0][0][0];       // 64 x 65 f32 = 16.6KB (<32KB)
  float* cmbD = cmb + 64*65;
  __syncthreads();                               // loop done
  if (jw == 1){
    #pragma unroll
    for (int rf=0; rf<2; rf++){
      #pragma unroll
      for (int ct=0; ct<4; ct++)
        #pragma unroll
        for (int r=0; r<4; r++)
          cmb[(rw*32 + rf*16 + g*4 + r)*65 + ct*16 + lr] = acc[rf][ct][r];
      if (lr == 0){
        #pragma unroll
        for (int r=0; r<4; r++)
          cmbD[rw*32 + rf*16 + g*4 + r] = accd[rf][r];
      }
    }
  }
  __syncthreads();
  if (jw == 0){
    #pragma unroll
    for (int rf=0; rf<2; rf++){
      #pragma unroll
      for (int r=0; r<4; r++){
        int rloc = rw*32 + rf*16 + g*4 + r;
        float d = accd[rf][r] + cmbD[rloc];
        float rd = 1.f / fmaxf(d, 1e-30f);
        int row = rowtile*64 + rloc;
        if (FINAL){
          size_t pbase = (size_t)((h<<JCLOG)|jc)*Nn + row;
          if (lr == 0) Dpart[pbase] = d;
          #pragma unroll
          for (int ct=0; ct<4; ct++){
            float v = acc[rf][ct][r] + cmb[rloc*65 + ct*16 + lr];
            Opart[pbase*64 + ct*16 + lr] = f2bf(v);   // raw partial (bf16: range)
          }
        } else {
          #pragma unroll
          for (int ct=0; ct<4; ct++){
            float v = (acc[rf][ct][r] + cmb[rloc*65 + ct*16 + lr]) * rd;
            v = v > 0.f ? v : __expf(v) - 1.f;   // ELU
            Hmat[(size_t)row*O1 + h*64 + ct*16 + lr] =
                __builtin_bit_cast(unsigned short, (_Float16)v);
          }
        }
      }
    }
  }
}

// ---- layer-2 finish: combine 8 j-chunks, normalize, ELU, log_softmax ----
__global__ void k_fin2(const unsigned short* __restrict__ Op, const float* __restrict__ Dp,
                       float* __restrict__ out){
  int w = threadIdx.x>>6, l = threadIdx.x&63;
  int row = blockIdx.x*4 + w;
  float o = 0.f, d = 0.f;
  #pragma unroll
  for (int jc=0; jc<8; jc++){
    o += bf2f(Op[((size_t)jc*Nn + row)*64 + l]);
    d += Dp[(size_t)jc*Nn + row];
  }
  float v = o / fmaxf(d, 1e-30f);
  v = v > 0.f ? v : __expf(v) - 1.f;
  float m = v;
  #pragma unroll
  for (int dd=1; dd<64; dd<<=1) m = fmaxf(m, __shfl_xor(m, dd));
  float s = __expf(v - m);
  #pragma unroll
  for (int dd=1; dd<64; dd<<=1) s += __shfl_xor(s, dd);
  out[(size_t)row*64 + l] = v - (m + __logf(s));
}

extern "C" void kernel_launch(void* const* d_in, const int* in_sizes, int n_in,
                              void* d_out, int out_size, void* d_ws, size_t ws_size,
                              hipStream_t stream){
  const float* x  = (const float*)d_in[0];
  const int* adj  = (const int*)d_in[1];
  const float* W  = (const float*)d_in[2];
  const float* a1 = (const float*)d_in[3];
  const float* a2 = (const float*)d_in[4];
  const float* W2 = (const float*)d_in[5];
  const float* a21= (const float*)d_in[6];
  const float* a22= (const float*)d_in[7];
  float* out = (float*)d_out;
  char* ws = (char*)d_ws;

  size_t off=0;
  ull* adjw = (ull*)(ws+off); off += (size_t)Nn*64*8;                                 // 2MB
  unsigned short* xb   = (unsigned short*)(ws+off); off += (size_t)Nn*FIN*2;          // 4MB
  unsigned short* Wb   = (unsigned short*)(ws+off); off += (size_t)O1*FIN*2;          // .5MB
  unsigned short* W2b  = (unsigned short*)(ws+off); off += (size_t)64*FIN*2;          // 64KB
  unsigned short* whT1 = (unsigned short*)(ws+off); off += (size_t)O1*Nn*2;           // 4MB
  unsigned short* Hmat = (unsigned short*)(ws+off); off += (size_t)Nn*O1*2;           // 4MB
  unsigned short* whT2 = (unsigned short*)(ws+off); off += (size_t)64*Nn*2;           // .5MB
  float2* e1f1a = (float2*)(ws+off); off += (size_t)NH*Nn*8;
  unsigned short* E2aa = (unsigned short*)(ws+off); off += (size_t)NH*Nn*2;
  unsigned short* F2aa = (unsigned short*)(ws+off); off += (size_t)NH*Nn*2;
  float2* e1f1b = (float2*)(ws+off); off += (size_t)Nn*8;
  unsigned short* E2ab = (unsigned short*)(ws+off); off += (size_t)Nn*2;
  unsigned short* F2ab = (unsigned short*)(ws+off); off += (size_t)Nn*2;
  // layer-2 partials: 8 slots x Nn x 64 bf16 (4MB) + 8 x Nn fp32 (128KB)
  unsigned short* Opart = (unsigned short*)(ws+off); off += (size_t)8*Nn*64*2;
  float* Dpart = (float*)(ws+off); off += (size_t)8*Nn*4;

  k_pack_adj<<<2048, 256, 0, stream>>>(adj, adjw);
  {
    int tot = (Nn*FIN + O1*FIN + 64*FIN)/4;
    k_cvt_all<<<(tot+255)/256, 256, 0, stream>>>(x, W, W2, xb, Wb, W2b);
  }
  k_gemm3<2,4><<<dim3(Nn/32, O1/64), 512, 0, stream>>>(xb, Wb, whT1, Nn, FIN, O1);
  k_wh12<<<dim3(Nn/256, NH), 256, 0, stream>>>(whT1, a1, a2, e1f1a, E2aa, F2aa);
  // layer-1 attention: 64 rowtiles x 8 heads = 512 blocks x 256 thr, direct Hmat
  k_attn14<32, 3, 0, 0><<<(Nn/64)*NH, 256, 0, stream>>>(adjw, e1f1a, E2aa, F2aa, whT1, Hmat, nullptr, nullptr);
  // layer-2 projection: o-tile 32, grid 128x2 = 256 blocks
  k_gemm3<1,8><<<dim3(Nn/32, 2), 512, 0, stream>>>(Hmat, W2b, whT2, Nn, FIN, 64);
  k_wh12<<<dim3(Nn/256, 1), 256, 0, stream>>>(whT2, a21, a22, e1f1b, E2ab, F2ab);
  // layer-2 attention: 64 rowtiles x 8 j-chunks = 512 blocks -> partials
  k_attn14<4, 0, 3, 1><<<(Nn/64)*8, 256, 0, stream>>>(adjw, e1f1b, E2ab, F2ab, whT2, nullptr, Opart, Dpart);
  k_fin2<<<Nn/4, 256, 0, stream>>>(Opart, Dpart, out);
  (void)in_sizes; (void)n_in; (void)out_size; (void)ws_size;
}